// Round 3
// baseline (428.689 us; speedup 1.0000x reference)
//
#include <hip/hip_runtime.h>
#include <hip/hip_bf16.h>
#include <math.h>

#define B_ 1024
#define S_ 200
#define D_ 128
#define H_ 128
#define N_ 64

typedef __attribute__((ext_vector_type(8))) short short8;
typedef __attribute__((ext_vector_type(8))) __bf16 bf16x8;
typedef __attribute__((ext_vector_type(4))) float floatx4;

typedef __attribute__((address_space(1))) void gvoid_t;
typedef __attribute__((address_space(3))) void lvoid_t;

static __device__ __forceinline__ float bf2f(unsigned short u) {
    union { unsigned int i; float f; } v; v.i = ((unsigned int)u) << 16; return v.f;
}
static __device__ __forceinline__ unsigned short f2bf(float f) {
    union { float f; unsigned int u; } v; v.f = f;
    unsigned int u = v.u;
    return (unsigned short)((u + 0x7FFFu + ((u >> 16) & 1u)) >> 16);   // RNE
}
static __device__ __forceinline__ float ld1(const void* p, int isbf, size_t i) {
    return isbf ? bf2f(((const unsigned short*)p)[i]) : ((const float*)p)[i];
}
static __device__ __forceinline__ float fast_tanh(float x) {
    float t = __expf(2.0f * x);
    return 1.0f - 2.0f * __builtin_amdgcn_rcpf(t + 1.0f);   // err ~2e-5
}
static __device__ __forceinline__ void gload_lds16(const void* g, void* l) {
    __builtin_amdgcn_global_load_lds((const gvoid_t*)g, (lvoid_t*)l, 16, 0, 0);
}

// ---- wave-local dtype detection (no barriers; every wave computes the same flag) ----
static __device__ __forceinline__ int detect_wave_256(const void* p) {
    int lane = threadIdx.x & 63;
    uint4 w = ((const uint4*)p)[lane];          // 256 words sampled per wave
    unsigned int ws[4] = {w.x, w.y, w.z, w.w};
    int pass = 0;
#pragma unroll
    for (int k = 0; k < 4; ++k) {
        unsigned int e = (ws[k] >> 7) & 0xFF;   // exponent of lo-bf16 if data is bf16
        pass += (e == 0 || (e >= 96 && e <= 140)) ? 1 : 0;
    }
#pragma unroll
    for (int off = 32; off; off >>= 1) pass += __shfl_xor(pass, off, 64);
    return pass * 4 >= 256 * 3;
}
static __device__ __forceinline__ int detect_wave_64(const void* p) {
    int lane = threadIdx.x & 63;
    unsigned int w = ((const unsigned int*)p)[lane];   // 64 words
    unsigned int e = (w >> 7) & 0xFF;
    int pass = (e == 0 || (e >= 96 && e <= 140)) ? 1 : 0;
#pragma unroll
    for (int off = 32; off; off >>= 1) pass += __shfl_xor(pass, off, 64);
    return pass * 4 >= 64 * 3;
}
static __device__ __forceinline__ int detect_mask_u8(const void* p) {
    int lane = threadIdx.x & 63;
    uint4 w = ((const uint4*)p)[lane];          // first 1 KB of mask
    unsigned int x = (w.x | w.y | w.z | w.w) & 0xFFFFFF00u;  // nonzero high bytes => u8
    return (__ballot(x != 0) != 0ULL) ? 1 : 0;
}

// ---------------- prep: block 0 -> WeTf (fragment-swizzled); blocks 1..200 -> pbL rows ----
// WeTf layout: frag = nt*4+kks; WeTf[(frag*64+lane)*8+j] = We[kks*32+(lane>>4)*8+j][nt*16+(lane&15)]
// pbL layout (per-lane C-fragment order): float idx ((mt*8+nt)*64 + quad*16 + mrow)*4 + reg
//   = pb[s = mt*16+quad*4+reg][h = nt*16+mrow]. mt=12 entries with s>=200 are zero-filled.
__global__ __launch_bounds__(128) void prep_kernel(
    const void* __restrict__ We, const void* __restrict__ pos,
    const void* __restrict__ Wp,
    unsigned short* __restrict__ WeTf, float* __restrict__ pbL)
{
    int blk = blockIdx.x, t = threadIdx.x;
    __shared__ unsigned short T[128][136];
    __shared__ float prow[D_];
    __shared__ int fl[2];
    if (blk == 0) {
        if (t < 64) { int f = detect_wave_256(We); if (t == 0) fl[0] = f; }
        __syncthreads();
        int fWe = fl[0];
        for (int c = t; c < 2048; c += 128) {
            int d = c >> 4, h8 = (c & 15) * 8;
            short8 v;
            if (fWe) {
                v = *(const short8*)((const unsigned short*)We + d * H_ + h8);
            } else {
                const float* p = (const float*)We + d * H_ + h8;
                float4 a = ((const float4*)p)[0], b = ((const float4*)p)[1];
                v[0] = (short)f2bf(a.x); v[1] = (short)f2bf(a.y);
                v[2] = (short)f2bf(a.z); v[3] = (short)f2bf(a.w);
                v[4] = (short)f2bf(b.x); v[5] = (short)f2bf(b.y);
                v[6] = (short)f2bf(b.z); v[7] = (short)f2bf(b.w);
            }
            *(short8*)(&T[d][h8]) = v;
        }
        __syncthreads();
        for (int i = t; i < 2048; i += 128) {
            int frag = i >> 6, ln = i & 63;
            int nt = frag >> 2, kks = frag & 3;
            int h = nt * 16 + (ln & 15);
            int dbase = kks * 32 + (ln >> 4) * 8;
            short8 v;
#pragma unroll
            for (int j = 0; j < 8; ++j) v[j] = (short)T[dbase + j][h];
            *(short8*)(WeTf + (size_t)i * 8) = v;
        }
        // zero-fill pbL entries for mt=12, s_local >= 8 (s = 200..207); disjoint from s<200 writers
        for (int i = t; i < 1024; i += 128) {
            int nt = i >> 7, j = i & 127;
            int q = 2 + (j >> 6), m = (j >> 2) & 15, r = j & 3;
            pbL[(((96 + nt) * 64 + q * 16 + m) << 2) + r] = 0.f;
        }
    } else {
        if (t < 64)       { int f = detect_wave_256(pos); if (t == 0)  fl[0] = f; }
        else if (t < 128) { int f = detect_wave_256(Wp);  if (t == 64) fl[1] = f; }
        __syncthreads();
        int fPos = fl[0], fWp = fl[1];
        int s = blk - 1, h = t;
        prow[h] = ld1(pos, fPos, (size_t)s * D_ + h);
        __syncthreads();
        float acc = 0.f;
        if (fWp) {
            const unsigned short* W = (const unsigned short*)Wp;
            for (int d = 0; d < D_; ++d) acc = fmaf(prow[d], bf2f(W[d * H_ + h]), acc);
        } else {
            const float* W = (const float*)Wp;
            for (int d = 0; d < D_; ++d) acc = fmaf(prow[d], W[d * H_ + h], acc);
        }
        int mt = s >> 4, qr = s & 15;
        int idx = (((mt * 8 + (h >> 4)) * 64 + (qr >> 2) * 16 + (h & 15)) << 2) + (qr & 3);
        pbL[idx] = acc;
    }
}

// ---------------- fused: ONE WAVE PER BATCH ROW, zero block barriers in main path ------
// Block = 256 thr (4 waves) sharing a read-only 32KB WeTf LDS copy. Wave w owns
// b = blockIdx*4+w: MFMA scores over 13 m-tiles with online-softmax (running m,l,O[2/lane])
// folding the attn-weighted X sum into the score loop (X HBM-fetched ONCE).
__global__ __launch_bounds__(256, 4) void fused_kernel(
    const void* __restrict__ Xs, const void* __restrict__ Xitem,
    const void* __restrict__ maskv, const void* __restrict__ origin,
    const unsigned short* __restrict__ WeTf, const float* __restrict__ pbL,
    const void* __restrict__ zv,
    float* __restrict__ pos_loss, float* __restrict__ neg_sum,
    float* __restrict__ out)
{
    int t = threadIdx.x;
    int wv = t >> 6, lane = t & 63;
    int quad = lane >> 4, mrow = lane & 15;
    int b = blockIdx.x * 4 + wv;
    int d0 = lane * 2;

    __shared__ __align__(16) unsigned short WeSh[16384];   // 32 KB
    __shared__ __align__(16) float outbuf[4 * D_];         // per-wave out_vec

    int fXs = detect_wave_256(Xs);
    int fXi = detect_wave_256(Xitem);
    int fOr = detect_wave_256(origin);
    int fz  = detect_wave_64(zv);
    int fMk = detect_mask_u8(maskv);

    // one-time WeTf -> LDS stage (linear dest = uniform base + lane*16)
    for (int i = t; i < 2048; i += 256)
        gload_lds16(WeTf + (size_t)i * 8, WeSh + (size_t)i * 8);

    const unsigned short* Xg16 = (const unsigned short*)Xs + (size_t)b * S_ * D_;
    const float*          Xg32 = (const float*)Xs + (size_t)b * S_ * D_;

    // --- early per-wave loads (land under staging latency) ---
    int len = 0;
    {
#pragma unroll
        for (int k = 0; k < 4; ++k) {
            int s = lane + 64 * k;
            int nzv = 0;
            if (s < S_)
                nzv = fMk ? (((const unsigned char*)maskv)[(size_t)b * S_ + s] != 0)
                          : (((const int*)maskv)[(size_t)b * S_ + s] != 0);
            len += __popcll(__ballot(nzv));
        }
    }
    int last = len - 1;
    float zr[8];
#pragma unroll
    for (int nt = 0; nt < 8; ++nt) zr[nt] = ld1(zv, fz, nt * 16 + mrow);
    float xi0, xi1;
    if (fXi) {
        unsigned int u = *(const unsigned int*)((const unsigned short*)Xitem + (size_t)b * D_ + d0);
        xi0 = bf2f((unsigned short)(u & 0xffff)); xi1 = bf2f((unsigned short)(u >> 16));
    } else {
        float2 v = *(const float2*)((const float*)Xitem + (size_t)b * D_ + d0);
        xi0 = v.x; xi1 = v.y;
    }

    asm volatile("s_waitcnt vmcnt(0)" ::: "memory");
    __syncthreads();   // the ONLY block barrier

    // ---- A-fragment loader (row-clamped for mt=12 tail) ----
#define LOADA(MT, AF)                                                              \
    {                                                                              \
        int r_ = (MT) * 16 + mrow; if (r_ > 199) r_ = 199;                         \
        if (fXs) {                                                                 \
            const unsigned short* p_ = Xg16 + (size_t)r_ * D_ + quad * 8;          \
            _Pragma("unroll")                                                      \
            for (int kk_ = 0; kk_ < 4; ++kk_)                                      \
                AF[kk_] = __builtin_bit_cast(bf16x8, *(const short8*)(p_ + kk_ * 32)); \
        } else {                                                                   \
            const float* p_ = Xg32 + (size_t)r_ * D_ + quad * 8;                   \
            _Pragma("unroll")                                                      \
            for (int kk_ = 0; kk_ < 4; ++kk_) {                                    \
                float4 a_ = ((const float4*)(p_ + kk_ * 32))[0];                   \
                float4 b2_ = ((const float4*)(p_ + kk_ * 32))[1];                  \
                short8 v_;                                                         \
                v_[0] = (short)f2bf(a_.x); v_[1] = (short)f2bf(a_.y);              \
                v_[2] = (short)f2bf(a_.z); v_[3] = (short)f2bf(a_.w);              \
                v_[4] = (short)f2bf(b2_.x); v_[5] = (short)f2bf(b2_.y);            \
                v_[6] = (short)f2bf(b2_.z); v_[7] = (short)f2bf(b2_.w);            \
                AF[kk_] = __builtin_bit_cast(bf16x8, v_);                          \
            }                                                                      \
        }                                                                          \
    }

#define LOADXP(R, X0, X1)                                                          \
    {                                                                              \
        if (fXs) {                                                                 \
            unsigned int u_ = *(const unsigned int*)(Xg16 + (size_t)(R) * D_ + d0);\
            X0 = bf2f((unsigned short)(u_ & 0xffff));                              \
            X1 = bf2f((unsigned short)(u_ >> 16));                                 \
        } else {                                                                   \
            float2 v_ = *(const float2*)(Xg32 + (size_t)(R) * D_ + d0);            \
            X0 = v_.x; X1 = v_.y;                                                  \
        }                                                                          \
    }

    bf16x8 afc[4], afn[4];
    LOADA(0, afc);

    float m_run = -INFINITY, l_run = 0.f;
    float O0 = 0.f, O1 = 0.f;
    float slv = -INFINITY;          // raw score of position `last`
    float dsc = 0.f;                // deferred rescale
    float de0 = 0.f, de1 = 0.f, de2 = 0.f, de3 = 0.f;   // deferred unnorm weights
    int dmt = 0;
    const float4* pb4 = (const float4*)pbL;

    for (int mt = 0; mt < 13; ++mt) {
        // pb for this tile -> future acc C-in (issue first: latency hides under O-update)
        float4 pbt[8];
#pragma unroll
        for (int nt = 0; nt < 8; ++nt)
            pbt[nt] = pb4[(size_t)(mt * 8 + nt) * 64 + lane];
        if (mt < 12) LOADA(mt + 1, afn);

        // ---- deferred O-update from previous tile (X rows still cache-hot) ----
        if (mt > 0) {
            O0 *= dsc; O1 *= dsc;
#pragma unroll
            for (int q = 0; q < 4; ++q) {
                float eq0 = q ? __shfl_xor(de0, q << 4, 64) : de0;
                float eq1 = q ? __shfl_xor(de1, q << 4, 64) : de1;
                float eq2 = q ? __shfl_xor(de2, q << 4, 64) : de2;
                float eq3 = q ? __shfl_xor(de3, q << 4, 64) : de3;
                int rb = (dmt << 4) + ((quad ^ q) << 2);
#pragma unroll
                for (int r = 0; r < 4; ++r) {
                    float es = (r == 0) ? eq0 : (r == 1) ? eq1 : (r == 2) ? eq2 : eq3;
                    int row = rb + r; if (row > 199) row = 199;
                    float x0, x1; LOADXP(row, x0, x1);
                    O0 = fmaf(es, x0, O0);
                    O1 = fmaf(es, x1, O1);
                }
            }
        }

        // ---- MFMA: acc init = pb (C-in), accumulate X·We over 4 K-steps ----
        floatx4 acc[8];
#pragma unroll
        for (int nt = 0; nt < 8; ++nt) {
            acc[nt][0] = pbt[nt].x; acc[nt][1] = pbt[nt].y;
            acc[nt][2] = pbt[nt].z; acc[nt][3] = pbt[nt].w;
        }
#pragma unroll
        for (int kks = 0; kks < 4; ++kks) {
#pragma unroll
            for (int nt = 0; nt < 8; ++nt) {
                short8 bv = *(const short8*)(WeSh + (size_t)(((nt << 2) + kks) * 64 + lane) * 8);
                acc[nt] = __builtin_amdgcn_mfma_f32_16x16x32_bf16(
                    afc[kks], __builtin_bit_cast(bf16x8, bv), acc[nt], 0, 0, 0);
            }
        }

        // ---- tanh -> z-dot -> butterfly over h (all lanes get tile scores) ----
        float val0, val1, val2, val3;
#pragma unroll
        for (int r = 0; r < 4; ++r) {
            float v = 0.f;
#pragma unroll
            for (int nt = 0; nt < 8; ++nt)
                v = fmaf(fast_tanh(acc[nt][r]), zr[nt], v);
            v += __shfl_xor(v, 1, 64);
            v += __shfl_xor(v, 2, 64);
            v += __shfl_xor(v, 4, 64);
            v += __shfl_xor(v, 8, 64);
            if (r == 0) val0 = v; else if (r == 1) val1 = v;
            else if (r == 2) val2 = v; else val3 = v;
        }

        // ---- online softmax tile statistics ----
        int sbase = (mt << 4) + (quad << 2);
        float x0m = (sbase + 0 < len) ? val0 : -INFINITY;
        float x1m = (sbase + 1 < len) ? val1 : -INFINITY;
        float x2m = (sbase + 2 < len) ? val2 : -INFINITY;
        float x3m = (sbase + 3 < len) ? val3 : -INFINITY;
        if (sbase + 0 == last) slv = val0;
        if (sbase + 1 == last) slv = val1;
        if (sbase + 2 == last) slv = val2;
        if (sbase + 3 == last) slv = val3;
        float tm = fmaxf(fmaxf(x0m, x1m), fmaxf(x2m, x3m));
        tm = fmaxf(tm, __shfl_xor(tm, 16, 64));
        tm = fmaxf(tm, __shfl_xor(tm, 32, 64));
        float mn = fmaxf(m_run, tm);
        float sc_ = __expf(m_run - mn);        // m_run=-inf on mt=0 -> 0
        de0 = (sbase + 0 < len) ? __expf(val0 - mn) : 0.f;
        de1 = (sbase + 1 < len) ? __expf(val1 - mn) : 0.f;
        de2 = (sbase + 2 < len) ? __expf(val2 - mn) : 0.f;
        de3 = (sbase + 3 < len) ? __expf(val3 - mn) : 0.f;
        float tl = de0 + de1 + de2 + de3;
        tl += __shfl_xor(tl, 16, 64);
        tl += __shfl_xor(tl, 32, 64);
        l_run = l_run * sc_ + tl;
        m_run = mn;
        dsc = sc_; dmt = mt;

#pragma unroll
        for (int kks = 0; kks < 4; ++kks) afc[kks] = afn[kks];
    }

    // ---- final deferred O-update (mt=12) ----
    {
        O0 *= dsc; O1 *= dsc;
#pragma unroll
        for (int q = 0; q < 4; ++q) {
            float eq0 = q ? __shfl_xor(de0, q << 4, 64) : de0;
            float eq1 = q ? __shfl_xor(de1, q << 4, 64) : de1;
            float eq2 = q ? __shfl_xor(de2, q << 4, 64) : de2;
            float eq3 = q ? __shfl_xor(de3, q << 4, 64) : de3;
            int rb = (12 << 4) + ((quad ^ q) << 2);
#pragma unroll
            for (int r = 0; r < 4; ++r) {
                float es = (r == 0) ? eq0 : (r == 1) ? eq1 : (r == 2) ? eq2 : eq3;
                int row = rb + r; if (row > 199) row = 199;
                float x0, x1; LOADXP(row, x0, x1);
                O0 = fmaf(es, x0, O0);
                O1 = fmaf(es, x1, O1);
            }
        }
    }

    // ---- epilogue: att, last_vec, out_vec, losses (all wave-local) ----
    float att0 = O0 / l_run, att1 = O1 / l_run;
    slv = fmaxf(slv, __shfl_xor(slv, 16, 64));
    slv = fmaxf(slv, __shfl_xor(slv, 32, 64));
    float al = __expf(slv - m_run) / l_run;     // attn[last]
    float xl0, xl1; LOADXP(last, xl0, xl1);
    float lv0 = al * xl0, lv1 = al * xl1;
    float ov0 = att0 - lv0, ov1 = att1 - lv1;
    float* outw = outbuf + wv * D_;
    outw[d0] = ov0; outw[d0 + 1] = ov1;

    float r0 = att0 * xi0 + att1 * xi1;         // inner
    float r1 = lv0 * lv0 + lv1 * lv1;
    float r2 = lv0 * ov0 + lv1 * ov1;
    float r3 = ov0 * ov0 + ov1 * ov1;
#pragma unroll
    for (int off = 32; off; off >>= 1) {
        r0 += __shfl_xor(r0, off, 64);
        r1 += __shfl_xor(r1, off, 64);
        r2 += __shfl_xor(r2, off, 64);
        r3 += __shfl_xor(r3, off, 64);
    }
    out[(size_t)b * (D_ + 1) + d0] = att0;
    out[(size_t)b * (D_ + 1) + d0 + 1] = att1;
    if (lane == 0) {
        out[(size_t)b * (D_ + 1) + D_] = r0;
        float cosv = r2 / (sqrtf(fmaxf(r1, 1e-12f)) * sqrtf(fmaxf(r3, 1e-12f)));
        float pl = 0.5f * (1.f - cosv);
        pos_loss[b] = log1pf(expf(-pl));
    }
    float vv = r3;                               // ||out_vec||^2 (all lanes)

    // ---- neg losses: lane owns n = lane; dot over 16 8-wide chunks ----
    {
        float oo = 0.f, ovd = 0.f;
        if (fOr) {
            const unsigned short* orow = (const unsigned short*)origin + ((size_t)b * N_ + lane) * D_;
#pragma unroll 4
            for (int j = 0; j < 16; ++j) {
                short8 og = *(const short8*)(orow + j * 8);
                float4 c0 = *(const float4*)(outw + j * 8);
                float4 c1 = *(const float4*)(outw + j * 8 + 4);
                float f0 = bf2f((unsigned short)og[0]), f1 = bf2f((unsigned short)og[1]);
                float f2 = bf2f((unsigned short)og[2]), f3 = bf2f((unsigned short)og[3]);
                float f4 = bf2f((unsigned short)og[4]), f5 = bf2f((unsigned short)og[5]);
                float f6 = bf2f((unsigned short)og[6]), f7 = bf2f((unsigned short)og[7]);
                oo  = fmaf(f0, f0, oo);  ovd = fmaf(f0, c0.x, ovd);
                oo  = fmaf(f1, f1, oo);  ovd = fmaf(f1, c0.y, ovd);
                oo  = fmaf(f2, f2, oo);  ovd = fmaf(f2, c0.z, ovd);
                oo  = fmaf(f3, f3, oo);  ovd = fmaf(f3, c0.w, ovd);
                oo  = fmaf(f4, f4, oo);  ovd = fmaf(f4, c1.x, ovd);
                oo  = fmaf(f5, f5, oo);  ovd = fmaf(f5, c1.y, ovd);
                oo  = fmaf(f6, f6, oo);  ovd = fmaf(f6, c1.z, ovd);
                oo  = fmaf(f7, f7, oo);  ovd = fmaf(f7, c1.w, ovd);
            }
        } else {
            const float* orow = (const float*)origin + ((size_t)b * N_ + lane) * D_;
#pragma unroll 4
            for (int j = 0; j < 16; ++j) {
                float4 g0 = *(const float4*)(orow + j * 8);
                float4 g1 = *(const float4*)(orow + j * 8 + 4);
                float4 c0 = *(const float4*)(outw + j * 8);
                float4 c1 = *(const float4*)(outw + j * 8 + 4);
                oo  = fmaf(g0.x, g0.x, oo);  ovd = fmaf(g0.x, c0.x, ovd);
                oo  = fmaf(g0.y, g0.y, oo);  ovd = fmaf(g0.y, c0.y, ovd);
                oo  = fmaf(g0.z, g0.z, oo);  ovd = fmaf(g0.z, c0.z, ovd);
                oo  = fmaf(g0.w, g0.w, oo);  ovd = fmaf(g0.w, c0.w, ovd);
                oo  = fmaf(g1.x, g1.x, oo);  ovd = fmaf(g1.x, c1.x, ovd);
                oo  = fmaf(g1.y, g1.y, oo);  ovd = fmaf(g1.y, c1.y, ovd);
                oo  = fmaf(g1.z, g1.z, oo);  ovd = fmaf(g1.z, c1.z, ovd);
                oo  = fmaf(g1.w, g1.w, oo);  ovd = fmaf(g1.w, c1.w, ovd);
            }
        }
        float cosn = ovd / (sqrtf(fmaxf(oo, 1e-12f)) * sqrtf(fmaxf(vv, 1e-12f)));
        float nl = 0.5f * (1.f - cosn);
        float nloss = log1pf(expf(nl));
#pragma unroll
        for (int off = 32; off; off >>= 1) nloss += __shfl_xor(nloss, off, 64);
        if (lane == 0) neg_sum[b] = nloss;
    }
#undef LOADA
#undef LOADXP
}

// ---------------- K3: aux[b] = sum_b'(pos_loss) + neg_sum[b] (f32) ----------------
__global__ __launch_bounds__(1024) void final_kernel(
    const float* __restrict__ pos_loss,
    const float* __restrict__ neg_sum,
    float* __restrict__ out)
{
    __shared__ float red[16];
    int t = threadIdx.x;
    float v = pos_loss[t];
    for (int off = 32; off; off >>= 1) v += __shfl_xor(v, off, 64);
    if ((t & 63) == 0) red[t >> 6] = v;
    __syncthreads();
    if (t == 0) {
        float s = 0.f;
#pragma unroll
        for (int i = 0; i < 16; ++i) s += red[i];
        red[0] = s;
    }
    __syncthreads();
    out[(size_t)B_ * (D_ + 1) + t] = red[0] + neg_sum[t];
}

extern "C" void kernel_launch(void* const* d_in, const int* in_sizes, int n_in,
                              void* d_out, int out_size, void* d_ws, size_t ws_size,
                              hipStream_t stream) {
    const void* Xs     = d_in[0]; // X_series [B,S,D]
    const void* pos    = d_in[1]; // pos_series [S,D]
    const void* Xitem  = d_in[2]; // X_item [B,D]
    const void* mask   = d_in[3]; // valid_mask [B,S]
    const void* origin = d_in[4]; // origin [B,N,D]
    const void* Wp     = d_in[5]; // [D,H]
    const void* We     = d_in[6]; // [D,H]
    const void* zv     = d_in[7]; // [H]

    unsigned short* WeTf = (unsigned short*)d_ws;                  // 32 KB swizzled
    float* pbL      = (float*)((char*)d_ws + 32768);               // 13*8*64*4 f32 = 104 KB
    float* pos_loss = pbL + 13 * 8 * 64 * 4;                       // 1024 f32
    float* neg_sum  = pos_loss + B_;                               // 1024 f32
    float* out = (float*)d_out;                                    // f32 output

    prep_kernel<<<201, 128, 0, stream>>>(We, pos, Wp, WeTf, pbL);
    fused_kernel<<<B_ / 4, 256, 0, stream>>>(Xs, Xitem, mask, origin, WeTf, pbL, zv,
                                             pos_loss, neg_sum, out);
    final_kernel<<<1, 1024, 0, stream>>>(pos_loss, neg_sum, out);
}

// Round 4
// 308.670 us; speedup vs baseline: 1.3888x; 1.3888x over previous
//
#include <hip/hip_runtime.h>
#include <hip/hip_bf16.h>
#include <math.h>

#define B_ 1024
#define S_ 200
#define D_ 128
#define H_ 128
#define N_ 64

typedef __attribute__((ext_vector_type(8))) short short8;
typedef __attribute__((ext_vector_type(8))) __bf16 bf16x8;
typedef __attribute__((ext_vector_type(4))) float floatx4;

static __device__ __forceinline__ float bf2f(unsigned short u) {
    union { unsigned int i; float f; } v; v.i = ((unsigned int)u) << 16; return v.f;
}
static __device__ __forceinline__ unsigned short f2bf(float f) {
    union { float f; unsigned int u; } v; v.f = f;
    unsigned int u = v.u;
    return (unsigned short)((u + 0x7FFFu + ((u >> 16) & 1u)) >> 16);   // RNE
}
static __device__ __forceinline__ float ld1(const void* p, int isbf, size_t i) {
    return isbf ? bf2f(((const unsigned short*)p)[i]) : ((const float*)p)[i];
}
static __device__ __forceinline__ float fast_tanh(float x) {
    float t = __expf(2.0f * x);
    return 1.0f - 2.0f * __builtin_amdgcn_rcpf(t + 1.0f);   // err ~2e-5
}

// ---- wave-local dtype detection (no barriers; every wave computes the same flag) ----
static __device__ __forceinline__ int detect_wave_256(const void* p) {
    int lane = threadIdx.x & 63;
    uint4 w = ((const uint4*)p)[lane];          // 256 words sampled per wave
    unsigned int ws[4] = {w.x, w.y, w.z, w.w};
    int pass = 0;
#pragma unroll
    for (int k = 0; k < 4; ++k) {
        unsigned int e = (ws[k] >> 7) & 0xFF;   // exponent of lo-bf16 if data is bf16
        pass += (e == 0 || (e >= 96 && e <= 140)) ? 1 : 0;
    }
#pragma unroll
    for (int off = 32; off; off >>= 1) pass += __shfl_xor(pass, off, 64);
    return pass * 4 >= 256 * 3;
}
static __device__ __forceinline__ int detect_wave_64(const void* p) {
    int lane = threadIdx.x & 63;
    unsigned int w = ((const unsigned int*)p)[lane];   // 64 words
    unsigned int e = (w >> 7) & 0xFF;
    int pass = (e == 0 || (e >= 96 && e <= 140)) ? 1 : 0;
#pragma unroll
    for (int off = 32; off; off >>= 1) pass += __shfl_xor(pass, off, 64);
    return pass * 4 >= 64 * 3;
}
static __device__ __forceinline__ int detect_mask_u8(const void* p) {
    int lane = threadIdx.x & 63;
    uint4 w = ((const uint4*)p)[lane];          // first 1 KB of mask
    unsigned int x = (w.x | w.y | w.z | w.w) & 0xFFFFFF00u;  // nonzero high bytes => u8
    return (__ballot(x != 0) != 0ULL) ? 1 : 0;
}

// ---------------- prep: block 0 -> WeTf (fragment-swizzled); blocks 1..200 -> pbL rows ----
// WeTf layout: frag = nt*4+kks; WeTf[(frag*64+lane)*8+j] = We[kks*32+(lane>>4)*8+j][nt*16+(lane&15)]
// pbL layout (per-lane C-fragment order): float idx ((mt*8+nt)*64 + quad*16 + mrow)*4 + reg
//   = pb[s = mt*16+quad*4+reg][h = nt*16+mrow]. mt=12 entries with s>=200 are zero-filled.
__global__ __launch_bounds__(128) void prep_kernel(
    const void* __restrict__ We, const void* __restrict__ pos,
    const void* __restrict__ Wp,
    unsigned short* __restrict__ WeTf, float* __restrict__ pbL)
{
    int blk = blockIdx.x, t = threadIdx.x;
    __shared__ unsigned short T[128][136];
    __shared__ float prow[D_];
    __shared__ int fl[2];
    if (blk == 0) {
        if (t < 64) { int f = detect_wave_256(We); if (t == 0) fl[0] = f; }
        __syncthreads();
        int fWe = fl[0];
        for (int c = t; c < 2048; c += 128) {
            int d = c >> 4, h8 = (c & 15) * 8;
            short8 v;
            if (fWe) {
                v = *(const short8*)((const unsigned short*)We + d * H_ + h8);
            } else {
                const float* p = (const float*)We + d * H_ + h8;
                float4 a = ((const float4*)p)[0], b = ((const float4*)p)[1];
                v[0] = (short)f2bf(a.x); v[1] = (short)f2bf(a.y);
                v[2] = (short)f2bf(a.z); v[3] = (short)f2bf(a.w);
                v[4] = (short)f2bf(b.x); v[5] = (short)f2bf(b.y);
                v[6] = (short)f2bf(b.z); v[7] = (short)f2bf(b.w);
            }
            *(short8*)(&T[d][h8]) = v;
        }
        __syncthreads();
        for (int i = t; i < 2048; i += 128) {
            int frag = i >> 6, ln = i & 63;
            int nt = frag >> 2, kks = frag & 3;
            int h = nt * 16 + (ln & 15);
            int dbase = kks * 32 + (ln >> 4) * 8;
            short8 v;
#pragma unroll
            for (int j = 0; j < 8; ++j) v[j] = (short)T[dbase + j][h];
            *(short8*)(WeTf + (size_t)i * 8) = v;
        }
        // zero-fill pbL entries for mt=12, s_local >= 8 (s = 200..207)
        for (int i = t; i < 1024; i += 128) {
            int nt = i >> 7, j = i & 127;
            int q = 2 + (j >> 6), m = (j >> 2) & 15, r = j & 3;
            pbL[(((96 + nt) * 64 + q * 16 + m) << 2) + r] = 0.f;
        }
    } else {
        if (t < 64)       { int f = detect_wave_256(pos); if (t == 0)  fl[0] = f; }
        else if (t < 128) { int f = detect_wave_256(Wp);  if (t == 64) fl[1] = f; }
        __syncthreads();
        int fPos = fl[0], fWp = fl[1];
        int s = blk - 1, h = t;
        prow[h] = ld1(pos, fPos, (size_t)s * D_ + h);
        __syncthreads();
        float acc = 0.f;
        if (fWp) {
            const unsigned short* W = (const unsigned short*)Wp;
            for (int d = 0; d < D_; ++d) acc = fmaf(prow[d], bf2f(W[d * H_ + h]), acc);
        } else {
            const float* W = (const float*)Wp;
            for (int d = 0; d < D_; ++d) acc = fmaf(prow[d], W[d * H_ + h], acc);
        }
        int mt = s >> 4, qr = s & 15;
        int idx = (((mt * 8 + (h >> 4)) * 64 + (qr >> 2) * 16 + (h & 15)) << 2) + (qr & 3);
        pbL[idx] = acc;
    }
}

// ---------------- fused: block per b, 8 waves (wave = n-tile), NO big LDS staging -------
// A-fragments stream from global (L1 merges the 8 waves' identical rows); B-fragments in
// registers; LDS only for score/attn/partial buffers (~18 KB) -> 3 blocks/CU.
__global__ __launch_bounds__(512, 6) void fused_kernel(
    const void* __restrict__ Xs, const void* __restrict__ Xitem,
    const void* __restrict__ maskv, const void* __restrict__ origin,
    const unsigned short* __restrict__ WeTf, const float* __restrict__ pbL,
    const void* __restrict__ zv,
    float* __restrict__ pos_loss, float* __restrict__ neg_sum,
    float* __restrict__ out)
{
    int b = blockIdx.x, t = threadIdx.x;
    int wv = t >> 6, lane = t & 63;
    int quad = lane >> 4, mrow = lane & 15;

    __shared__ __align__(16) float ubuf[4096];   // sp[8][208] | partial[32][128] | p_oo/p_ov
    __shared__ float attn[256];
    __shared__ float outv[D_];
    __shared__ float red[32];

    int fXs = detect_wave_256(Xs);
    int fXi = detect_wave_256(Xitem);
    int fOr = detect_wave_256(origin);
    int fz  = detect_wave_64(zv);
    int fMk = detect_mask_u8(maskv);

    const unsigned short* Xg16 = (const unsigned short*)Xs + (size_t)b * S_ * D_;
    const float*          Xg32 = (const float*)Xs + (size_t)b * S_ * D_;

    // --- length via 4 wave ballots (every wave computes it; no LDS) ---
    int len = 0;
#pragma unroll
    for (int k = 0; k < 4; ++k) {
        int s = lane + 64 * k;
        int nzv = 0;
        if (s < S_)
            nzv = fMk ? (((const unsigned char*)maskv)[(size_t)b * S_ + s] != 0)
                      : (((const int*)maskv)[(size_t)b * S_ + s] != 0);
        len += __popcll(__ballot(nzv));
    }
    int last = len - 1;

    // --- per-wave constants: B fragments (regs), z slice, pb base, Xitem ---
    int nt = wv;
    bf16x8 bfr[4];
#pragma unroll
    for (int kks = 0; kks < 4; ++kks)
        bfr[kks] = __builtin_bit_cast(bf16x8,
            *(const short8*)(WeTf + (size_t)((((nt << 2) + kks) << 6) + lane) * 8));
    float zl = ld1(zv, fz, nt * 16 + mrow);
    const float4* pb4 = (const float4*)pbL;
    float xiv = (t < D_) ? ld1(Xitem, fXi, (size_t)b * D_ + t) : 0.f;

#define LOADA(MT, AF)                                                              \
    {                                                                              \
        int r_ = (MT) * 16 + mrow; if (r_ > 199) r_ = 199;                         \
        if (fXs) {                                                                 \
            const unsigned short* p_ = Xg16 + (size_t)r_ * D_ + quad * 8;          \
            _Pragma("unroll")                                                      \
            for (int kk_ = 0; kk_ < 4; ++kk_)                                      \
                AF[kk_] = __builtin_bit_cast(bf16x8, *(const short8*)(p_ + kk_ * 32)); \
        } else {                                                                   \
            const float* p_ = Xg32 + (size_t)r_ * D_ + quad * 8;                   \
            _Pragma("unroll")                                                      \
            for (int kk_ = 0; kk_ < 4; ++kk_) {                                    \
                float4 a_ = ((const float4*)(p_ + kk_ * 32))[0];                   \
                float4 b2_ = ((const float4*)(p_ + kk_ * 32))[1];                  \
                short8 v_;                                                         \
                v_[0] = (short)f2bf(a_.x); v_[1] = (short)f2bf(a_.y);              \
                v_[2] = (short)f2bf(a_.z); v_[3] = (short)f2bf(a_.w);              \
                v_[4] = (short)f2bf(b2_.x); v_[5] = (short)f2bf(b2_.y);            \
                v_[6] = (short)f2bf(b2_.z); v_[7] = (short)f2bf(b2_.w);            \
                AF[kk_] = __builtin_bit_cast(bf16x8, v_);                          \
            }                                                                      \
        }                                                                          \
    }

    // --- phase A: 13 m-tiles, wave computes its nt partial of the z-dot ---
    bf16x8 afc[4], afn[4];
    LOADA(0, afc);
    float4 pbc = pb4[(size_t)(0 * 8 + nt) * 64 + lane];
    float* sp = ubuf;   // [8][208]

    for (int mt = 0; mt < 13; ++mt) {
        float4 pbn = pbc;
        if (mt < 12) {
            LOADA(mt + 1, afn);
            pbn = pb4[(size_t)((mt + 1) * 8 + nt) * 64 + lane];
        }
        floatx4 acc;
        acc[0] = pbc.x; acc[1] = pbc.y; acc[2] = pbc.z; acc[3] = pbc.w;
#pragma unroll
        for (int kks = 0; kks < 4; ++kks)
            acc = __builtin_amdgcn_mfma_f32_16x16x32_bf16(afc[kks], bfr[kks], acc, 0, 0, 0);
#pragma unroll
        for (int r = 0; r < 4; ++r) {
            float v = fast_tanh(acc[r]) * zl;
            v += __shfl_xor(v, 1, 64);
            v += __shfl_xor(v, 2, 64);
            v += __shfl_xor(v, 4, 64);
            v += __shfl_xor(v, 8, 64);
            int s = mt * 16 + quad * 4 + r;
            if (mrow == 0 && s < S_) sp[nt * 208 + s] = v;
        }
#pragma unroll
        for (int kks = 0; kks < 4; ++kks) afc[kks] = afn[kks];
        pbc = pbn;
    }
    __syncthreads();                                           // S1: sp ready

    // --- softmax by wave 0 (registers + shuffles), writes attn[0..255] ---
    if (wv == 0) {
        float s0 = 0.f, s1 = 0.f, s2 = 0.f, s3 = 0.f;
#pragma unroll
        for (int n8 = 0; n8 < 8; ++n8) {
            float4 q = *(const float4*)(sp + n8 * 208 + lane * 4);
            s0 += q.x; s1 += q.y; s2 += q.z; s3 += q.w;
        }
        int sb = lane * 4;
        float m0 = (sb + 0 < len) ? s0 : -INFINITY;
        float m1 = (sb + 1 < len) ? s1 : -INFINITY;
        float m2 = (sb + 2 < len) ? s2 : -INFINITY;
        float m3 = (sb + 3 < len) ? s3 : -INFINITY;
        float m = fmaxf(fmaxf(m0, m1), fmaxf(m2, m3));
#pragma unroll
        for (int off = 32; off; off >>= 1) m = fmaxf(m, __shfl_xor(m, off, 64));
        float e0 = (sb + 0 < len) ? __expf(s0 - m) : 0.f;
        float e1 = (sb + 1 < len) ? __expf(s1 - m) : 0.f;
        float e2 = (sb + 2 < len) ? __expf(s2 - m) : 0.f;
        float e3 = (sb + 3 < len) ? __expf(s3 - m) : 0.f;
        float l = e0 + e1 + e2 + e3;
#pragma unroll
        for (int off = 32; off; off >>= 1) l += __shfl_xor(l, off, 64);
        float inv = 1.0f / l;
        float4 av = {e0 * inv, e1 * inv, e2 * inv, e3 * inv};
        *(float4*)(attn + sb) = av;
    }
    __syncthreads();                                           // S2: attn ready

    // --- weighted sum: partial[32][128] from GLOBAL X (L2/L3-hot) ---
    {
        int spi = t >> 4;          // 0..31
        int d8 = (t & 15) * 8;     // 0..120
        float a0 = 0.f, a1 = 0.f, a2 = 0.f, a3 = 0.f;
        float a4 = 0.f, a5 = 0.f, a6 = 0.f, a7 = 0.f;
        if (fXs) {
            for (int s = spi; s < S_; s += 32) {
                float ww = attn[s];
                short8 v2 = *(const short8*)(Xg16 + (size_t)s * D_ + d8);
                a0 = fmaf(ww, bf2f((unsigned short)v2[0]), a0);
                a1 = fmaf(ww, bf2f((unsigned short)v2[1]), a1);
                a2 = fmaf(ww, bf2f((unsigned short)v2[2]), a2);
                a3 = fmaf(ww, bf2f((unsigned short)v2[3]), a3);
                a4 = fmaf(ww, bf2f((unsigned short)v2[4]), a4);
                a5 = fmaf(ww, bf2f((unsigned short)v2[5]), a5);
                a6 = fmaf(ww, bf2f((unsigned short)v2[6]), a6);
                a7 = fmaf(ww, bf2f((unsigned short)v2[7]), a7);
            }
        } else {
            for (int s = spi; s < S_; s += 32) {
                float ww = attn[s];
                const float* p = Xg32 + (size_t)s * D_ + d8;
                float4 u0 = ((const float4*)p)[0], u1 = ((const float4*)p)[1];
                a0 = fmaf(ww, u0.x, a0); a1 = fmaf(ww, u0.y, a1);
                a2 = fmaf(ww, u0.z, a2); a3 = fmaf(ww, u0.w, a3);
                a4 = fmaf(ww, u1.x, a4); a5 = fmaf(ww, u1.y, a5);
                a6 = fmaf(ww, u1.z, a6); a7 = fmaf(ww, u1.w, a7);
            }
        }
        float4 w0 = {a0, a1, a2, a3}, w1 = {a4, a5, a6, a7};
        *(float4*)(ubuf + spi * D_ + d8)     = w0;   // sp is dead now
        *(float4*)(ubuf + spi * D_ + d8 + 4) = w1;
    }
    __syncthreads();                                           // S3: partial ready

    // --- epilogue reductions (waves 0-1), out write ---
    if (t < D_) {
        float att = 0.f;
#pragma unroll
        for (int p = 0; p < 32; ++p) att += ubuf[p * D_ + t];
        float xl = fXs ? bf2f(Xg16[(size_t)last * D_ + t])
                       : Xg32[(size_t)last * D_ + t];
        float lv = attn[last] * xl;
        float ov = att - lv;                 // out_vec = attention_output - last_vec
        outv[t] = ov;
        out[(size_t)b * (D_ + 1) + t] = att;
        float r0 = att * xiv;                // inner
        float r1 = lv * lv, r2 = lv * ov, r3 = ov * ov;
#pragma unroll
        for (int off = 32; off; off >>= 1) {
            r0 += __shfl_xor(r0, off, 64);
            r1 += __shfl_xor(r1, off, 64);
            r2 += __shfl_xor(r2, off, 64);
            r3 += __shfl_xor(r3, off, 64);
        }
        if (lane == 0) { red[wv] = r0; red[8 + wv] = r1; red[16 + wv] = r2; red[24 + wv] = r3; }
    }
    __syncthreads();                                           // S4: red/outv ready, ubuf free
    float vv = red[24] + red[25];            // ||out_vec||^2 (all threads)
    if (t == 0) {
        out[(size_t)b * (D_ + 1) + D_] = red[0] + red[1];
        float ll = red[8] + red[9], lo = red[16] + red[17];
        float cosv = lo / (sqrtf(fmaxf(ll, 1e-12f)) * sqrtf(fmaxf(vv, 1e-12f)));
        float pl = 0.5f * (1.f - cosv);
        pos_loss[b] = log1pf(expf(-pl));
    }

    // --- neg losses: thread (nn = t>>3, part = t&7) eighth-dot; origin loaded here ---
    {
        int nn = t >> 3, part = t & 7;
        float o_f[16];
        if (fOr) {
            const unsigned short* p = (const unsigned short*)origin + ((size_t)b * N_ + nn) * D_ + part * 16;
#pragma unroll
            for (int j = 0; j < 2; ++j) {
                uint4 u = *(const uint4*)(p + j * 8);
                o_f[j*8+0] = bf2f((unsigned short)(u.x & 0xffff));
                o_f[j*8+1] = bf2f((unsigned short)(u.x >> 16));
                o_f[j*8+2] = bf2f((unsigned short)(u.y & 0xffff));
                o_f[j*8+3] = bf2f((unsigned short)(u.y >> 16));
                o_f[j*8+4] = bf2f((unsigned short)(u.z & 0xffff));
                o_f[j*8+5] = bf2f((unsigned short)(u.z >> 16));
                o_f[j*8+6] = bf2f((unsigned short)(u.w & 0xffff));
                o_f[j*8+7] = bf2f((unsigned short)(u.w >> 16));
            }
        } else {
            const float* p = (const float*)origin + ((size_t)b * N_ + nn) * D_ + part * 16;
#pragma unroll
            for (int j = 0; j < 4; ++j) {
                float4 v = *(const float4*)(p + j * 4);
                o_f[j*4+0] = v.x; o_f[j*4+1] = v.y; o_f[j*4+2] = v.z; o_f[j*4+3] = v.w;
            }
        }
        float o_oo = 0.f, o_ov = 0.f;
#pragma unroll
        for (int j = 0; j < 16; ++j) {
            float wv_ = outv[part * 16 + j];
            o_oo = fmaf(o_f[j], o_f[j], o_oo);
            o_ov = fmaf(o_f[j], wv_, o_ov);
        }
        float* p_oo = ubuf;          // [8][64]
        float* p_ov = ubuf + 512;    // [8][64]
        p_oo[part * 64 + nn] = o_oo;
        p_ov[part * 64 + nn] = o_ov;
        __syncthreads();                                       // S5
        if (t < 64) {
            float oo = 0.f, ov2 = 0.f;
#pragma unroll
            for (int p8 = 0; p8 < 8; ++p8) { oo += p_oo[p8 * 64 + t]; ov2 += p_ov[p8 * 64 + t]; }
            float cosn = ov2 / (sqrtf(fmaxf(oo, 1e-12f)) * sqrtf(fmaxf(vv, 1e-12f)));
            float nl = 0.5f * (1.f - cosn);
            float nloss = log1pf(expf(nl));
#pragma unroll
            for (int off = 32; off; off >>= 1) nloss += __shfl_xor(nloss, off, 64);
            if (t == 0) neg_sum[b] = nloss;
        }
    }
#undef LOADA
}

// ---------------- K3: aux[b] = sum_b'(pos_loss) + neg_sum[b] (f32) ----------------
__global__ __launch_bounds__(1024) void final_kernel(
    const float* __restrict__ pos_loss,
    const float* __restrict__ neg_sum,
    float* __restrict__ out)
{
    __shared__ float red[16];
    int t = threadIdx.x;
    float v = pos_loss[t];
    for (int off = 32; off; off >>= 1) v += __shfl_xor(v, off, 64);
    if ((t & 63) == 0) red[t >> 6] = v;
    __syncthreads();
    if (t == 0) {
        float s = 0.f;
#pragma unroll
        for (int i = 0; i < 16; ++i) s += red[i];
        red[0] = s;
    }
    __syncthreads();
    out[(size_t)B_ * (D_ + 1) + t] = red[0] + neg_sum[t];
}

extern "C" void kernel_launch(void* const* d_in, const int* in_sizes, int n_in,
                              void* d_out, int out_size, void* d_ws, size_t ws_size,
                              hipStream_t stream) {
    const void* Xs     = d_in[0]; // X_series [B,S,D]
    const void* pos    = d_in[1]; // pos_series [S,D]
    const void* Xitem  = d_in[2]; // X_item [B,D]
    const void* mask   = d_in[3]; // valid_mask [B,S]
    const void* origin = d_in[4]; // origin [B,N,D]
    const void* Wp     = d_in[5]; // [D,H]
    const void* We     = d_in[6]; // [D,H]
    const void* zv     = d_in[7]; // [H]

    unsigned short* WeTf = (unsigned short*)d_ws;                  // 32 KB swizzled
    float* pbL      = (float*)((char*)d_ws + 32768);               // 13*8*64*4 f32 = 104 KB
    float* pos_loss = pbL + 13 * 8 * 64 * 4;                       // 1024 f32
    float* neg_sum  = pos_loss + B_;                               // 1024 f32
    float* out = (float*)d_out;                                    // f32 output

    prep_kernel<<<201, 128, 0, stream>>>(We, pos, Wp, WeTf, pbL);
    fused_kernel<<<B_, 512, 0, stream>>>(Xs, Xitem, mask, origin, WeTf, pbL, zv,
                                         pos_loss, neg_sum, out);
    final_kernel<<<1, 1024, 0, stream>>>(pos_loss, neg_sum, out);
}